// Round 6
// baseline (51.811 us; speedup 1.0000x reference)
//
#include <hip/hip_runtime.h>

#define BB 4
#define RR 160
#define HH 128
#define WW 128
#define CC 64
#define NREG 32
#define PH 7
#define PW 7
#define IOU_THRF 0.4f

// floor division (Python // semantics) for possibly-negative numerators
__device__ __forceinline__ int fdiv(int a, int b) {
    int q = a / b, r = a % b;
    return (r != 0 && ((r < 0) != (b < 0))) ? q - 1 : q;
}

__device__ __forceinline__ void fix_span(int& lo, int& hi, int p, int s) {
    int pad = p - (hi - lo);
    bool fmin = lo < fdiv(pad, 2);
    bool fmax = (s - hi) < fdiv(1 + pad, 2);
    bool sym = (pad > 0) && !(fmin || fmax);
    int lo2 = sym ? lo - fdiv(pad, 2) : lo;
    int hi2 = sym ? hi + fdiv(1 + pad, 2) : hi;
    if ((pad > 0) && fmin) { lo2 = 0; hi2 = p; }
    if ((pad > 0) && fmax) { lo2 = s - p; hi2 = s; }
    lo = lo2; hi = hi2;
}

// One block per (b, region n, pool-row half). Ballot-based NMS mask build
// (all 64 lanes compute one IoU row-chunk per step -> one ballot word),
// inverted-mask register scan (k &= nsup|mb), per-thread select of box n,
// clip, then pool 3-4 pool-rows x 7 pool-cols striped over 8 waves.
__global__ __launch_bounds__(512)
void fused_roipool(const float* __restrict__ feat, const float* __restrict__ roi,
                   float* __restrict__ out) {
    const int g = blockIdx.x;
    const int ihalf = g & 1;            // 0: pool rows 0-3, 1: rows 4-6
    const int pair  = g >> 1;           // 0..127
    const int n = pair & (NREG - 1);
    const int b = pair >> 5;
    const int tid  = threadIdx.x;
    const int wid  = tid >> 6;          // 0..7
    const int lane = tid & 63;

    __shared__ float sx[RR], sy[RR], sx1[RR], sy1[RR], sarea[RR];
    __shared__ unsigned long long nsup[RR][3];   // ~suppression words

    // ---- load boxes for batch b ----
    const float* rb = roi + (size_t)b * RR * 4;
    if (tid < RR) {
        float x = rb[tid * 4 + 0], y = rb[tid * 4 + 1];
        float w = rb[tid * 4 + 2], h = rb[tid * 4 + 3];
        sx[tid] = x; sy[tid] = y;
        sx1[tid] = __fadd_rn(x, w);
        sy1[tid] = __fadd_rn(y, h);
        sarea[tid] = __fmul_rn(w, h);
    }
    __syncthreads();

    // ---- ballot mask build: batch = (row t, 64-bit word w); 351 batches.
    // t in [0,64): words 0,1,2 ; t in [64,128): words 1,2 ; t in [128,159): word 2.
    for (int bi = wid; bi < 351; bi += 8) {
        int t, w;
        if (bi < 192)      { t = bi / 3;                 w = bi % 3; }
        else if (bi < 320) { int r2 = bi - 192; t = 64 + (r2 >> 1); w = 1 + (r2 & 1); }
        else               { t = 128 + (bi - 320);       w = 2; }
        const int j  = w * 64 + lane;
        const int jc = j < RR ? j : RR - 1;
        const float xa = fmaxf(sx[t], sx[jc]);
        const float ya = fmaxf(sy[t], sy[jc]);
        const float xb = fminf(sx1[t], sx1[jc]);
        const float yb = fminf(sy1[t], sy1[jc]);
        const float iw  = fmaxf(__fsub_rn(xb, xa), 0.0f);
        const float ihh = fmaxf(__fsub_rn(yb, ya), 0.0f);
        const float inter = __fmul_rn(iw, ihh);
        const float denom = __fsub_rn(__fadd_rn(sarea[t], sarea[jc]), inter);
        const bool pred = (j > t) && (j < RR) && (__fdiv_rn(inter, denom) > IOU_THRF);
        const unsigned long long bal = __ballot(pred);
        if (lane == 0) nsup[t][w] = ~bal;
    }
    __syncthreads();

    // ---- sequential keep-scan (exact lax.scan semantics), OR-AND form:
    // mb = keepbit-1 (all-ones when t not kept -> no-op; 0 when kept -> k &= nsup)
    unsigned long long k0 = ~0ull, k1 = ~0ull, k2 = (1ull << 32) - 1;
    #pragma unroll 8
    for (int t = 0; t < 64; ++t) {
        unsigned long long mb = ((k0 >> t) & 1ull) - 1ull;
        k0 &= nsup[t][0] | mb;
        k1 &= nsup[t][1] | mb;
        k2 &= nsup[t][2] | mb;
    }
    #pragma unroll 8
    for (int t = 64; t < 128; ++t) {
        unsigned long long mb = ((k1 >> (t - 64)) & 1ull) - 1ull;
        k1 &= nsup[t][1] | mb;
        k2 &= nsup[t][2] | mb;
    }
    #pragma unroll 8
    for (int t = 128; t < RR - 1; ++t) {
        unsigned long long mb = ((k2 >> (t - 128)) & 1ull) - 1ull;
        k2 &= nsup[t][2] | mb;
    }

    // ---- select the n-th kept box (pad: box RR-1); uniform across block ----
    int src = RR - 1;
    {
        int target = n;
        unsigned long long words[3] = {k0, k1, k2};
        #pragma unroll
        for (int w = 0; w < 3; ++w) {
            int pc = __popcll(words[w]);
            if (target < pc) {
                unsigned long long x = words[w];
                for (int q = 0; q < target; ++q) x &= x - 1;
                src = w * 64 + (__ffsll((long long)x) - 1);
                break;
            }
            target -= pc;
        }
    }

    // ---- clip (exact _clip_rois / _fix_span port) ----
    int x0 = max(0, (int)sx[src]);
    int y0 = max(0, (int)sy[src]);
    int x1 = min(WW, (int)sx1[src]);
    int y1 = min(HH, (int)sy1[src]);
    fix_span(x0, x1, PW, WW);
    fix_span(y0, y1, PH, HH);
    const int bw = x1 - x0, bh = y1 - y0;

    // ---- pool: tasks (pool-row il, pool-col jj) striped over 8 waves.
    // Lane = (pixel-group poff, channel-quad cq): float4 x 64 lanes = 1024B
    // coalesced; tail pixels clamp to c1-1 (duplicate max harmless).
    const int poff = lane >> 4;
    const int cq   = lane & 15;
    const int hs = bh / PH, wsz = bw / PW;
    const float* fb = feat + (size_t)b * HH * WW * CC;
    const int ntasks = ihalf ? 21 : 28;

    for (int task = wid; task < ntasks; task += 8) {
        const int il = task / 7, jj = task % 7;
        const int i = ihalf * 4 + il;
        const int r0 = y0 + i * hs;
        const int r1 = (i == PH - 1) ? (y0 + bh) : (r0 + hs);
        const int c0 = x0 + jj * wsz;
        const int c1 = (jj == PW - 1) ? (x0 + bw) : (c0 + wsz);

        float4 v = make_float4(-INFINITY, -INFINITY, -INFINITY, -INFINITY);
        for (int r = r0; r < r1; ++r) {
            const float* rowp = fb + (size_t)(r * WW) * CC;
            for (int base = c0; base < c1; base += 4) {
                int px = base + poff;
                px = px < c1 ? px : c1 - 1;
                const float4 tv = *reinterpret_cast<const float4*>(rowp + (size_t)px * CC + cq * 4);
                v.x = fmaxf(v.x, tv.x);
                v.y = fmaxf(v.y, tv.y);
                v.z = fmaxf(v.z, tv.z);
                v.w = fmaxf(v.w, tv.w);
            }
        }
        // reduce over the 4 pixel-groups: lanes {cq, cq+16, cq+32, cq+48}
        v.x = fmaxf(v.x, __shfl_xor(v.x, 16));
        v.y = fmaxf(v.y, __shfl_xor(v.y, 16));
        v.z = fmaxf(v.z, __shfl_xor(v.z, 16));
        v.w = fmaxf(v.w, __shfl_xor(v.w, 16));
        v.x = fmaxf(v.x, __shfl_xor(v.x, 32));
        v.y = fmaxf(v.y, __shfl_xor(v.y, 32));
        v.z = fmaxf(v.z, __shfl_xor(v.z, 32));
        v.w = fmaxf(v.w, __shfl_xor(v.w, 32));

        if (poff == 0) {
            float4* o = reinterpret_cast<float4*>(
                out + ((((size_t)b * NREG + n) * PH + i) * PW + jj) * CC) + cq;
            *o = v;
        }
    }
}

extern "C" void kernel_launch(void* const* d_in, const int* in_sizes, int n_in,
                              void* d_out, int out_size, void* d_ws, size_t ws_size,
                              hipStream_t stream) {
    const float* features = (const float*)d_in[0];
    const float* roi      = (const float*)d_in[1];
    float* out = (float*)d_out;

    fused_roipool<<<2 * BB * NREG, 512, 0, stream>>>(features, roi, out);
}

// Round 7
// 43.593 us; speedup vs baseline: 1.1885x; 1.1885x over previous
//
#include <hip/hip_runtime.h>

#define BB 4
#define RR 160
#define HH 128
#define WW 128
#define CC 64
#define NREG 32
#define PH 7
#define PW 7
#define IOU_THRF 0.4f

// floor division (Python // semantics) for possibly-negative numerators
__device__ __forceinline__ int fdiv(int a, int b) {
    int q = a / b, r = a % b;
    return (r != 0 && ((r < 0) != (b < 0))) ? q - 1 : q;
}

__device__ __forceinline__ void fix_span(int& lo, int& hi, int p, int s) {
    int pad = p - (hi - lo);
    bool fmin = lo < fdiv(pad, 2);
    bool fmax = (s - hi) < fdiv(1 + pad, 2);
    bool sym = (pad > 0) && !(fmin || fmax);
    int lo2 = sym ? lo - fdiv(pad, 2) : lo;
    int hi2 = sym ? hi + fdiv(1 + pad, 2) : hi;
    if ((pad > 0) && fmin) { lo2 = 0; hi2 = p; }
    if ((pad > 0) && fmax) { lo2 = s - p; hi2 = s; }
    lo = lo2; hi = hi2;
}

// One block per batch (4 blocks, 512 thr). Ballot mask-build: all 64 lanes
// of a wave compute one IoU row-chunk simultaneously -> one 64-bit word per
// ballot, no divergent per-lane loops. Inverted-mask register scan, select
// first 32 kept (pad box RR-1), clip, write int boxes to ws.
__global__ __launch_bounds__(512)
void nms_clip_kernel(const float* __restrict__ roi, int* __restrict__ boxes_out) {
    const int b = blockIdx.x;
    const int tid = threadIdx.x;
    const int wid = tid >> 6;
    const int lane = tid & 63;

    __shared__ float sx[RR], sy[RR], sx1[RR], sy1[RR], sarea[RR];
    __shared__ unsigned long long nsup[RR][3];   // ~suppression words

    const float* rb = roi + (size_t)b * RR * 4;
    if (tid < RR) {
        float x = rb[tid * 4 + 0], y = rb[tid * 4 + 1];
        float w = rb[tid * 4 + 2], h = rb[tid * 4 + 3];
        sx[tid] = x; sy[tid] = y;
        sx1[tid] = __fadd_rn(x, w);
        sy1[tid] = __fadd_rn(y, h);
        sarea[tid] = __fmul_rn(w, h);
    }
    __syncthreads();

    // ballot batches: t<64 -> words {0,1,2}; t in [64,128) -> {1,2}; t in [128,159) -> {2}
    for (int bi = wid; bi < 351; bi += 8) {
        int t, w;
        if (bi < 192)      { t = bi / 3;                 w = bi % 3; }
        else if (bi < 320) { int r2 = bi - 192; t = 64 + (r2 >> 1); w = 1 + (r2 & 1); }
        else               { t = 128 + (bi - 320);       w = 2; }
        const int j  = w * 64 + lane;
        const int jc = j < RR ? j : RR - 1;
        const float xa = fmaxf(sx[t], sx[jc]);
        const float ya = fmaxf(sy[t], sy[jc]);
        const float xb = fminf(sx1[t], sx1[jc]);
        const float yb = fminf(sy1[t], sy1[jc]);
        const float iw  = fmaxf(__fsub_rn(xb, xa), 0.0f);
        const float ihh = fmaxf(__fsub_rn(yb, ya), 0.0f);
        const float inter = __fmul_rn(iw, ihh);
        const float denom = __fsub_rn(__fadd_rn(sarea[t], sarea[jc]), inter);
        const bool pred = (j > t) && (j < RR) && (__fdiv_rn(inter, denom) > IOU_THRF);
        const unsigned long long bal = __ballot(pred);
        if (lane == 0) nsup[t][w] = ~bal;
    }
    __syncthreads();

    if (tid >= 64) return;

    // sequential keep-scan (exact lax.scan semantics), OR-AND form:
    // mb = keepbit-1: all-ones when t not kept (no-op), 0 when kept (k &= nsup)
    unsigned long long k0 = ~0ull, k1 = ~0ull, k2 = (1ull << 32) - 1;
    #pragma unroll 8
    for (int t = 0; t < 64; ++t) {
        unsigned long long mb = ((k0 >> t) & 1ull) - 1ull;
        k0 &= nsup[t][0] | mb;
        k1 &= nsup[t][1] | mb;
        k2 &= nsup[t][2] | mb;
    }
    #pragma unroll 8
    for (int t = 64; t < 128; ++t) {
        unsigned long long mb = ((k1 >> (t - 64)) & 1ull) - 1ull;
        k1 &= nsup[t][1] | mb;
        k2 &= nsup[t][2] | mb;
    }
    #pragma unroll 8
    for (int t = 128; t < RR - 1; ++t) {
        unsigned long long mb = ((k2 >> (t - 128)) & 1ull) - 1ull;
        k2 &= nsup[t][2] | mb;
    }

    if (tid >= NREG) return;

    // select the tid-th kept box (pad: box RR-1)
    int src = RR - 1;
    {
        int target = tid;
        unsigned long long words[3] = {k0, k1, k2};
        #pragma unroll
        for (int w = 0; w < 3; ++w) {
            int pc = __popcll(words[w]);
            if (target < pc) {
                unsigned long long x = words[w];
                for (int q = 0; q < target; ++q) x &= x - 1;
                src = w * 64 + (__ffsll((long long)x) - 1);
                break;
            }
            target -= pc;
        }
    }

    int x0 = max(0, (int)sx[src]);
    int y0 = max(0, (int)sy[src]);
    int x1 = min(WW, (int)sx1[src]);
    int y1 = min(HH, (int)sy1[src]);
    fix_span(x0, x1, PW, WW);
    fix_span(y0, y1, PH, HH);
    int* o = boxes_out + ((size_t)b * NREG + tid) * 4;
    o[0] = x0; o[1] = y0; o[2] = x1 - x0; o[3] = y1 - y0;
}

// One block per (b, region, pool-row i); one wave per pool-col jj.
// Lane = (pixel-group poff 0..3, channel-quad cq 0..15): each wave-load is
// float4 x 64 lanes = 1024B coalesced. Column loop is COMPILE-TIME 6 iters
// (max needed: last cell cols <= 24 -> 6 groups) with clamped indices and 6
// INDEPENDENT accumulators -> 6 loads in flight per row, no load depends on
// any accumulator; redundant groups re-read the tail cacheline (L1 hit,
// duplicate max harmless). Final 4-way cross-lane max via __shfl_xor.
__global__ __launch_bounds__(PW * CC)
void pool_kernel(const float* __restrict__ feat, const int* __restrict__ boxes,
                 float* __restrict__ out) {
    const int blk = blockIdx.x;
    const int i = blk % PH;
    const int n = (blk / PH) % NREG;
    const int b = blk / (PH * NREG);
    const int wave = threadIdx.x >> 6;   // jj, 0..6 (wave-uniform)
    const int lane = threadIdx.x & 63;
    const int poff = lane >> 4;          // 0..3  pixel offset within group
    const int cq   = lane & 15;          // 0..15 channel quad

    const int4 bx = *reinterpret_cast<const int4*>(boxes + ((size_t)b * NREG + n) * 4);
    const int x0 = bx.x, y0 = bx.y, w = bx.z, h = bx.w;
    const int hs = h / PH, wsz = w / PW;

    const int r0 = y0 + i * hs;
    const int r1 = (i == PH - 1) ? (y0 + h) : (r0 + hs);
    const int c0 = x0 + wave * wsz;
    const int c1 = (wave == PW - 1) ? (x0 + w) : (c0 + wsz);

    const float* fb = feat + (size_t)b * HH * WW * CC;

    float4 v[6];
    #pragma unroll
    for (int g = 0; g < 6; ++g)
        v[g] = make_float4(-INFINITY, -INFINITY, -INFINITY, -INFINITY);

    for (int r = r0; r < r1; ++r) {
        const float* rowp = fb + (size_t)(r * WW) * CC;
        #pragma unroll
        for (int g = 0; g < 6; ++g) {
            int px = c0 + g * 4 + poff;
            px = px < c1 ? px : c1 - 1;
            const float4 t = *reinterpret_cast<const float4*>(rowp + (size_t)px * CC + cq * 4);
            v[g].x = fmaxf(v[g].x, t.x);
            v[g].y = fmaxf(v[g].y, t.y);
            v[g].z = fmaxf(v[g].z, t.z);
            v[g].w = fmaxf(v[g].w, t.w);
        }
    }
    float4 a = v[0];
    #pragma unroll
    for (int g = 1; g < 6; ++g) {
        a.x = fmaxf(a.x, v[g].x);
        a.y = fmaxf(a.y, v[g].y);
        a.z = fmaxf(a.z, v[g].z);
        a.w = fmaxf(a.w, v[g].w);
    }
    // reduce over the 4 pixel-groups: lanes {cq, cq+16, cq+32, cq+48}
    a.x = fmaxf(a.x, __shfl_xor(a.x, 16));
    a.y = fmaxf(a.y, __shfl_xor(a.y, 16));
    a.z = fmaxf(a.z, __shfl_xor(a.z, 16));
    a.w = fmaxf(a.w, __shfl_xor(a.w, 16));
    a.x = fmaxf(a.x, __shfl_xor(a.x, 32));
    a.y = fmaxf(a.y, __shfl_xor(a.y, 32));
    a.z = fmaxf(a.z, __shfl_xor(a.z, 32));
    a.w = fmaxf(a.w, __shfl_xor(a.w, 32));

    if (poff == 0) {
        float4* o = reinterpret_cast<float4*>(
            out + ((((size_t)b * NREG + n) * PH + i) * PW + wave) * CC) + cq;
        *o = a;
    }
}

extern "C" void kernel_launch(void* const* d_in, const int* in_sizes, int n_in,
                              void* d_out, int out_size, void* d_ws, size_t ws_size,
                              hipStream_t stream) {
    const float* features = (const float*)d_in[0];
    const float* roi      = (const float*)d_in[1];
    float* out = (float*)d_out;
    int* boxes = (int*)d_ws;   // BB*NREG*4 ints = 2 KB

    nms_clip_kernel<<<BB, 512, 0, stream>>>(roi, boxes);
    pool_kernel<<<BB * NREG * PH, PW * CC, 0, stream>>>(features, boxes, out);
}

// Round 8
// 34.419 us; speedup vs baseline: 1.5053x; 1.2665x over previous
//
#include <hip/hip_runtime.h>

#define BB 4
#define RR 160
#define HH 128
#define WW 128
#define CC 64
#define NREG 32
#define PH 7
#define PW 7
#define IOU_THRF 0.4f

// floor division (Python // semantics) for possibly-negative numerators
__device__ __forceinline__ int fdiv(int a, int b) {
    int q = a / b, r = a % b;
    return (r != 0 && ((r < 0) != (b < 0))) ? q - 1 : q;
}

__device__ __forceinline__ void fix_span(int& lo, int& hi, int p, int s) {
    int pad = p - (hi - lo);
    bool fmin = lo < fdiv(pad, 2);
    bool fmax = (s - hi) < fdiv(1 + pad, 2);
    bool sym = (pad > 0) && !(fmin || fmax);
    int lo2 = sym ? lo - fdiv(pad, 2) : lo;
    int hi2 = sym ? hi + fdiv(1 + pad, 2) : hi;
    if ((pad > 0) && fmin) { lo2 = 0; hi2 = p; }
    if ((pad > 0) && fmax) { lo2 = s - p; hi2 = s; }
    lo = lo2; hi = hi2;
}

// One block per batch (4 blocks, 512 thr). Ballot mask-build: all 64 lanes
// of a wave compute one IoU row-chunk simultaneously -> one 64-bit word per
// ballot (stride-1 LDS reads, no divergent per-lane loops). Inverted-mask
// register scan on wave 0, select first 32 kept (pad box RR-1), clip,
// write int boxes to ws.
__global__ __launch_bounds__(512)
void nms_clip_kernel(const float* __restrict__ roi, int* __restrict__ boxes_out) {
    const int b = blockIdx.x;
    const int tid = threadIdx.x;
    const int wid = tid >> 6;
    const int lane = tid & 63;

    __shared__ float sx[RR], sy[RR], sx1[RR], sy1[RR], sarea[RR];
    __shared__ unsigned long long nsup[RR][3];   // ~suppression words

    const float* rb = roi + (size_t)b * RR * 4;
    if (tid < RR) {
        float x = rb[tid * 4 + 0], y = rb[tid * 4 + 1];
        float w = rb[tid * 4 + 2], h = rb[tid * 4 + 3];
        sx[tid] = x; sy[tid] = y;
        sx1[tid] = __fadd_rn(x, w);
        sy1[tid] = __fadd_rn(y, h);
        sarea[tid] = __fmul_rn(w, h);
    }
    __syncthreads();

    // ballot batches: t<64 -> words {0,1,2}; t in [64,128) -> {1,2}; t in [128,159) -> {2}
    for (int bi = wid; bi < 351; bi += 8) {
        int t, w;
        if (bi < 192)      { t = bi / 3;                 w = bi % 3; }
        else if (bi < 320) { int r2 = bi - 192; t = 64 + (r2 >> 1); w = 1 + (r2 & 1); }
        else               { t = 128 + (bi - 320);       w = 2; }
        const int j  = w * 64 + lane;
        const int jc = j < RR ? j : RR - 1;
        const float xa = fmaxf(sx[t], sx[jc]);
        const float ya = fmaxf(sy[t], sy[jc]);
        const float xb = fminf(sx1[t], sx1[jc]);
        const float yb = fminf(sy1[t], sy1[jc]);
        const float iw  = fmaxf(__fsub_rn(xb, xa), 0.0f);
        const float ihh = fmaxf(__fsub_rn(yb, ya), 0.0f);
        const float inter = __fmul_rn(iw, ihh);
        const float denom = __fsub_rn(__fadd_rn(sarea[t], sarea[jc]), inter);
        const bool pred = (j > t) && (j < RR) && (__fdiv_rn(inter, denom) > IOU_THRF);
        const unsigned long long bal = __ballot(pred);
        if (lane == 0) nsup[t][w] = ~bal;
    }
    __syncthreads();

    if (tid >= 64) return;

    // sequential keep-scan (exact lax.scan semantics), OR-AND form:
    // mb = keepbit-1: all-ones when t not kept (no-op), 0 when kept (k &= nsup)
    unsigned long long k0 = ~0ull, k1 = ~0ull, k2 = (1ull << 32) - 1;
    #pragma unroll 8
    for (int t = 0; t < 64; ++t) {
        unsigned long long mb = ((k0 >> t) & 1ull) - 1ull;
        k0 &= nsup[t][0] | mb;
        k1 &= nsup[t][1] | mb;
        k2 &= nsup[t][2] | mb;
    }
    #pragma unroll 8
    for (int t = 64; t < 128; ++t) {
        unsigned long long mb = ((k1 >> (t - 64)) & 1ull) - 1ull;
        k1 &= nsup[t][1] | mb;
        k2 &= nsup[t][2] | mb;
    }
    #pragma unroll 8
    for (int t = 128; t < RR - 1; ++t) {
        unsigned long long mb = ((k2 >> (t - 128)) & 1ull) - 1ull;
        k2 &= nsup[t][2] | mb;
    }

    if (tid >= NREG) return;

    // select the tid-th kept box (pad: box RR-1)
    int src = RR - 1;
    {
        int target = tid;
        unsigned long long words[3] = {k0, k1, k2};
        #pragma unroll
        for (int w = 0; w < 3; ++w) {
            int pc = __popcll(words[w]);
            if (target < pc) {
                unsigned long long x = words[w];
                for (int q = 0; q < target; ++q) x &= x - 1;
                src = w * 64 + (__ffsll((long long)x) - 1);
                break;
            }
            target -= pc;
        }
    }

    int x0 = max(0, (int)sx[src]);
    int y0 = max(0, (int)sy[src]);
    int x1 = min(WW, (int)sx1[src]);
    int y1 = min(HH, (int)sy1[src]);
    fix_span(x0, x1, PW, WW);
    fix_span(y0, y1, PH, HH);
    int* o = boxes_out + ((size_t)b * NREG + tid) * 4;
    o[0] = x0; o[1] = y0; o[2] = x1 - x0; o[3] = y1 - y0;
}

// ROUND-5 POOL, verbatim: one block per (b, region, pool-row i); one wave per
// pool-col jj. XCD-affinity remap keeps a region's 7 row-blocks on one XCD.
// Lane = (pixel-group poff 0..3, channel-quad cq 0..15): float4 x 64 lanes =
// 1024B coalesced; runtime column loop (loads independent of the fmax chain);
// tail pixels clamp to c1-1. 4-way cross-lane max via __shfl_xor(16/32).
__global__ __launch_bounds__(PW * CC)
void pool_kernel(const float* __restrict__ feat, const int* __restrict__ boxes,
                 float* __restrict__ out) {
    // bijective decode: xcd x = g%8 owns (b,n) pairs [x*16, x*16+16)
    const int g = blockIdx.x;
    const int x = g & 7;          // XCD slot
    const int q = g >> 3;         // 0..111
    const int pair = x * 16 + q / 7;   // 0..127
    const int i = q % 7;               // pool row
    const int n = pair & (NREG - 1);
    const int b = pair >> 5;

    const int wave = threadIdx.x >> 6;   // jj, 0..6 (wave-uniform)
    const int lane = threadIdx.x & 63;
    const int poff = lane >> 4;          // 0..3  pixel offset within group
    const int cq   = lane & 15;          // 0..15 channel quad

    const int4 bx = *reinterpret_cast<const int4*>(boxes + ((size_t)b * NREG + n) * 4);
    const int x0 = bx.x, y0 = bx.y, w = bx.z, h = bx.w;
    const int hs = h / PH, wsz = w / PW;

    const int r0 = y0 + i * hs;
    const int r1 = (i == PH - 1) ? (y0 + h) : (r0 + hs);
    const int c0 = x0 + wave * wsz;
    const int c1 = (wave == PW - 1) ? (x0 + w) : (c0 + wsz);

    const float* fb = feat + (size_t)b * HH * WW * CC;
    float4 v = make_float4(-INFINITY, -INFINITY, -INFINITY, -INFINITY);
    #pragma unroll 2
    for (int r = r0; r < r1; ++r) {
        const float* rowp = fb + (size_t)(r * WW) * CC;
        for (int base = c0; base < c1; base += 4) {
            int px = base + poff;
            px = px < c1 ? px : c1 - 1;
            const float4 t = *reinterpret_cast<const float4*>(rowp + (size_t)px * CC + cq * 4);
            v.x = fmaxf(v.x, t.x);
            v.y = fmaxf(v.y, t.y);
            v.z = fmaxf(v.z, t.z);
            v.w = fmaxf(v.w, t.w);
        }
    }
    // reduce over the 4 pixel-groups: lanes {cq, cq+16, cq+32, cq+48}
    v.x = fmaxf(v.x, __shfl_xor(v.x, 16));
    v.y = fmaxf(v.y, __shfl_xor(v.y, 16));
    v.z = fmaxf(v.z, __shfl_xor(v.z, 16));
    v.w = fmaxf(v.w, __shfl_xor(v.w, 16));
    v.x = fmaxf(v.x, __shfl_xor(v.x, 32));
    v.y = fmaxf(v.y, __shfl_xor(v.y, 32));
    v.z = fmaxf(v.z, __shfl_xor(v.z, 32));
    v.w = fmaxf(v.w, __shfl_xor(v.w, 32));

    if (poff == 0) {
        float4* o = reinterpret_cast<float4*>(
            out + ((((size_t)b * NREG + n) * PH + i) * PW + wave) * CC) + cq;
        *o = v;
    }
}

extern "C" void kernel_launch(void* const* d_in, const int* in_sizes, int n_in,
                              void* d_out, int out_size, void* d_ws, size_t ws_size,
                              hipStream_t stream) {
    const float* features = (const float*)d_in[0];
    const float* roi      = (const float*)d_in[1];
    float* out = (float*)d_out;
    int* boxes = (int*)d_ws;   // BB*NREG*4 ints = 2 KB

    nms_clip_kernel<<<BB, 512, 0, stream>>>(roi, boxes);
    pool_kernel<<<BB * NREG * PH, PW * CC, 0, stream>>>(features, boxes, out);
}

// Round 9
// 28.164 us; speedup vs baseline: 1.8396x; 1.2221x over previous
//
#include <hip/hip_runtime.h>

#define BB 4
#define RR 160
#define HH 128
#define WW 128
#define CC 64
#define NREG 32
#define PH 7
#define PW 7
#define IOU_THRF 0.4f

// floor division (Python // semantics) for possibly-negative numerators
__device__ __forceinline__ int fdiv(int a, int b) {
    int q = a / b, r = a % b;
    return (r != 0 && ((r < 0) != (b < 0))) ? q - 1 : q;
}

__device__ __forceinline__ void fix_span(int& lo, int& hi, int p, int s) {
    int pad = p - (hi - lo);
    bool fmin = lo < fdiv(pad, 2);
    bool fmax = (s - hi) < fdiv(1 + pad, 2);
    bool sym = (pad > 0) && !(fmin || fmax);
    int lo2 = sym ? lo - fdiv(pad, 2) : lo;
    int hi2 = sym ? hi + fdiv(1 + pad, 2) : hi;
    if ((pad > 0) && fmin) { lo2 = 0; hi2 = p; }
    if ((pad > 0) && fmax) { lo2 = s - p; hi2 = s; }
    lo = lo2; hi = hi2;
}

// One block per batch, 1024 threads (16 waves). Ballot mask-build with a
// STATIC wave->(word w, t-range) map: each lane's box-j fields are
// loop-invariant (hoisted to registers once); per step only 5 wave-uniform
// LDS broadcasts of row t remain, pipelined by unroll. Then inverted-mask
// register scan on wave 0, select first 32 kept, clip, write boxes to ws.
__global__ __launch_bounds__(1024)
void nms_clip_kernel(const float* __restrict__ roi, int* __restrict__ boxes_out) {
    const int b = blockIdx.x;
    const int tid = threadIdx.x;
    const int wid = tid >> 6;
    const int lane = tid & 63;

    __shared__ float sx[RR], sy[RR], sx1[RR], sy1[RR], sarea[RR];
    __shared__ unsigned long long nsup[RR][3];   // ~suppression words

    const float* rb = roi + (size_t)b * RR * 4;
    if (tid < RR) {
        const float4 r4 = reinterpret_cast<const float4*>(rb)[tid];
        sx[tid] = r4.x; sy[tid] = r4.y;
        sx1[tid] = __fadd_rn(r4.x, r4.z);
        sy1[tid] = __fadd_rn(r4.y, r4.w);
        sarea[tid] = __fmul_rn(r4.z, r4.w);
    }
    __syncthreads();

    // static wave -> (word w, [tlo,thi)) map covering exactly the words the
    // scan reads: w0 for t<64, w1 for t<128, w2 for t<159.
    {
        int w, tlo, thi;
        if (wid < 3)      { w = 0; tlo = wid * 64 / 3;              thi = (wid + 1) * 64 / 3; }
        else if (wid < 9) { w = 1; int c = wid - 3; tlo = c * 128 / 6; thi = (c + 1) * 128 / 6; }
        else              { w = 2; int c = wid - 9; tlo = c * 159 / 7; thi = (c + 1) * 159 / 7; }

        const int j  = w * 64 + lane;
        const int jc = j < RR ? j : RR - 1;
        // loop-invariant lane-box fields (registers)
        const float jx0 = sx[jc], jy0 = sy[jc], jx1 = sx1[jc], jy1 = sy1[jc], ja = sarea[jc];
        const bool jok = j < RR;

        #pragma unroll 4
        for (int t = tlo; t < thi; ++t) {
            const float xa = fmaxf(sx[t], jx0);
            const float ya = fmaxf(sy[t], jy0);
            const float xb = fminf(sx1[t], jx1);
            const float yb = fminf(sy1[t], jy1);
            const float iw  = fmaxf(__fsub_rn(xb, xa), 0.0f);
            const float ihh = fmaxf(__fsub_rn(yb, ya), 0.0f);
            const float inter = __fmul_rn(iw, ihh);
            const float denom = __fsub_rn(__fadd_rn(sarea[t], ja), inter);
            const bool pred = jok && (j > t) && (__fdiv_rn(inter, denom) > IOU_THRF);
            const unsigned long long bal = __ballot(pred);
            if (lane == 0) nsup[t][w] = ~bal;
        }
    }
    __syncthreads();

    if (tid >= 64) return;

    // sequential keep-scan (exact lax.scan semantics), OR-AND form:
    // mb = keepbit-1: all-ones when t not kept (no-op), 0 when kept (k &= nsup)
    unsigned long long k0 = ~0ull, k1 = ~0ull, k2 = (1ull << 32) - 1;
    #pragma unroll 8
    for (int t = 0; t < 64; ++t) {
        unsigned long long mb = ((k0 >> t) & 1ull) - 1ull;
        k0 &= nsup[t][0] | mb;
        k1 &= nsup[t][1] | mb;
        k2 &= nsup[t][2] | mb;
    }
    #pragma unroll 8
    for (int t = 64; t < 128; ++t) {
        unsigned long long mb = ((k1 >> (t - 64)) & 1ull) - 1ull;
        k1 &= nsup[t][1] | mb;
        k2 &= nsup[t][2] | mb;
    }
    #pragma unroll 8
    for (int t = 128; t < RR - 1; ++t) {
        unsigned long long mb = ((k2 >> (t - 128)) & 1ull) - 1ull;
        k2 &= nsup[t][2] | mb;
    }

    if (tid >= NREG) return;

    // select the tid-th kept box (pad: box RR-1)
    int src = RR - 1;
    {
        int target = tid;
        unsigned long long words[3] = {k0, k1, k2};
        #pragma unroll
        for (int w = 0; w < 3; ++w) {
            int pc = __popcll(words[w]);
            if (target < pc) {
                unsigned long long x = words[w];
                for (int q = 0; q < target; ++q) x &= x - 1;
                src = w * 64 + (__ffsll((long long)x) - 1);
                break;
            }
            target -= pc;
        }
    }

    int x0 = max(0, (int)sx[src]);
    int y0 = max(0, (int)sy[src]);
    int x1 = min(WW, (int)sx1[src]);
    int y1 = min(HH, (int)sy1[src]);
    fix_span(x0, x1, PW, WW);
    fix_span(y0, y1, PH, HH);
    int* o = boxes_out + ((size_t)b * NREG + tid) * 4;
    o[0] = x0; o[1] = y0; o[2] = x1 - x0; o[3] = y1 - y0;
}

// ROUND-5 POOL, verbatim: one block per (b, region, pool-row i); one wave per
// pool-col jj. XCD-affinity remap keeps a region's 7 row-blocks on one XCD.
// Lane = (pixel-group poff 0..3, channel-quad cq 0..15): float4 x 64 lanes =
// 1024B coalesced; runtime column loop; tail pixels clamp to c1-1.
// 4-way cross-lane max via __shfl_xor(16/32).
__global__ __launch_bounds__(PW * CC)
void pool_kernel(const float* __restrict__ feat, const int* __restrict__ boxes,
                 float* __restrict__ out) {
    // bijective decode: xcd x = g%8 owns (b,n) pairs [x*16, x*16+16)
    const int g = blockIdx.x;
    const int x = g & 7;          // XCD slot
    const int q = g >> 3;         // 0..111
    const int pair = x * 16 + q / 7;   // 0..127
    const int i = q % 7;               // pool row
    const int n = pair & (NREG - 1);
    const int b = pair >> 5;

    const int wave = threadIdx.x >> 6;   // jj, 0..6 (wave-uniform)
    const int lane = threadIdx.x & 63;
    const int poff = lane >> 4;          // 0..3  pixel offset within group
    const int cq   = lane & 15;          // 0..15 channel quad

    const int4 bx = *reinterpret_cast<const int4*>(boxes + ((size_t)b * NREG + n) * 4);
    const int x0 = bx.x, y0 = bx.y, w = bx.z, h = bx.w;
    const int hs = h / PH, wsz = w / PW;

    const int r0 = y0 + i * hs;
    const int r1 = (i == PH - 1) ? (y0 + h) : (r0 + hs);
    const int c0 = x0 + wave * wsz;
    const int c1 = (wave == PW - 1) ? (x0 + w) : (c0 + wsz);

    const float* fb = feat + (size_t)b * HH * WW * CC;
    float4 v = make_float4(-INFINITY, -INFINITY, -INFINITY, -INFINITY);
    #pragma unroll 2
    for (int r = r0; r < r1; ++r) {
        const float* rowp = fb + (size_t)(r * WW) * CC;
        for (int base = c0; base < c1; base += 4) {
            int px = base + poff;
            px = px < c1 ? px : c1 - 1;
            const float4 t = *reinterpret_cast<const float4*>(rowp + (size_t)px * CC + cq * 4);
            v.x = fmaxf(v.x, t.x);
            v.y = fmaxf(v.y, t.y);
            v.z = fmaxf(v.z, t.z);
            v.w = fmaxf(v.w, t.w);
        }
    }
    // reduce over the 4 pixel-groups: lanes {cq, cq+16, cq+32, cq+48}
    v.x = fmaxf(v.x, __shfl_xor(v.x, 16));
    v.y = fmaxf(v.y, __shfl_xor(v.y, 16));
    v.z = fmaxf(v.z, __shfl_xor(v.z, 16));
    v.w = fmaxf(v.w, __shfl_xor(v.w, 16));
    v.x = fmaxf(v.x, __shfl_xor(v.x, 32));
    v.y = fmaxf(v.y, __shfl_xor(v.y, 32));
    v.z = fmaxf(v.z, __shfl_xor(v.z, 32));
    v.w = fmaxf(v.w, __shfl_xor(v.w, 32));

    if (poff == 0) {
        float4* o = reinterpret_cast<float4*>(
            out + ((((size_t)b * NREG + n) * PH + i) * PW + wave) * CC) + cq;
        *o = v;
    }
}

extern "C" void kernel_launch(void* const* d_in, const int* in_sizes, int n_in,
                              void* d_out, int out_size, void* d_ws, size_t ws_size,
                              hipStream_t stream) {
    const float* features = (const float*)d_in[0];
    const float* roi      = (const float*)d_in[1];
    float* out = (float*)d_out;
    int* boxes = (int*)d_ws;   // BB*NREG*4 ints = 2 KB

    nms_clip_kernel<<<BB, 1024, 0, stream>>>(roi, boxes);
    pool_kernel<<<BB * NREG * PH, PW * CC, 0, stream>>>(features, boxes, out);
}